// Round 8
// baseline (12.745 us; speedup 1.0000x reference)
//
#include <hip/hip_runtime.h>

// LegendreActivation: out[b,o] = sum_w coeffs[o,w] * S[b,w]
// where S[b,w] = sum_i P_w(tanh(x[b,i]*scale)),  S[b,0] == 1024 exactly.
//
// R8: occupancy-for-latency. R7's packed f32 was a dead end (157 TF spec IS
// the scalar rate on CDNA4) — reverted to R6 scalar core. New: fit 8 waves/
// SIMD (launch_bounds(256,8), VGPR<=64) by shrinking phase 2 to 2 outputs/
// thread x 2 passes (18 coeff regs instead of 36). More resident waves hide
// exp2/rcp latency, global-load latency, and the barrier drain at whatever
// clock the chip is actually running.

constexpr int I_DIM = 1024;
constexpr int O_DIM = 1024;
constexpr int NT    = 256;   // 4 waves
constexpr int G     = 4;     // rows per block, one wave per row

typedef float f32x4 __attribute__((ext_vector_type(4)));
typedef float f32x2 __attribute__((ext_vector_type(2)));

__global__ __launch_bounds__(NT, 8) void legendre_fused(
    const float* __restrict__ x,
    const float* __restrict__ coeffs,
    const float* __restrict__ scale_p,
    float* __restrict__ out)
{
    __shared__ f32x4 S_lds[G][2];   // per-row Legendre sums S1..S8 as 2x float4

    const int t    = threadIdx.x;
    const int wave = t >> 6;        // 0..3 -> owns row b0+wave
    const int lane = t & 63;
    const int b0   = blockIdx.x * G;
    const int row  = b0 + wave;

    // ---- issue x loads + pass-A coeff loads up front ----
    const float4* xr = reinterpret_cast<const float4*>(x + (size_t)row * I_DIM) + lane;
    float4 xv0 = xr[0];
    float4 xv1 = xr[64];
    float4 xv2 = xr[128];
    float4 xv3 = xr[192];

    // pass A: o = 2t, 2t+1  -> 18 contiguous floats at coeffs + 18*t (8B aligned)
    const f32x2* cpA = reinterpret_cast<const f32x2*>(coeffs + 18 * (size_t)t);
    float ca[18];
    #pragma unroll
    for (int k = 0; k < 9; ++k) {
        f32x2 v = cpA[k];
        ca[2 * k] = v.x; ca[2 * k + 1] = v.y;
    }

    float sc = fminf(fmaxf(scale_p[0], 0.1f), 2.0f);
    const float K = sc * 2.8853900817779268f;  // sc * 2*log2(e)

    // ---- phase 1: power sums M_1..M_8 over one row (64 lanes x 16) ----
    float m1 = 0.f, m2 = 0.f, m3 = 0.f, m4 = 0.f,
          m5 = 0.f, m6 = 0.f, m7 = 0.f, m8 = 0.f;

    const float vals[16] = {xv0.x, xv0.y, xv0.z, xv0.w,
                            xv1.x, xv1.y, xv1.z, xv1.w,
                            xv2.x, xv2.y, xv2.z, xv2.w,
                            xv3.x, xv3.y, xv3.z, xv3.w};
    #pragma unroll
    for (int e = 0; e < 16; ++e) {
        float ex = __builtin_amdgcn_exp2f(vals[e] * K);               // e^{2z}
        float xs = fmaf(-2.f, __builtin_amdgcn_rcpf(ex + 1.f), 1.f);  // tanh
        float p2 = xs * xs;
        float p3 = p2 * xs;
        float p4 = p2 * p2;
        m1 += xs;
        m2 += p2;
        m3 += p3;
        m4 += p4;
        m5 = fmaf(p2, p3, m5);
        m6 = fmaf(p3, p3, m6);
        m7 = fmaf(p3, p4, m7);
        m8 = fmaf(p4, p4, m8);
    }

    // 64-lane butterfly: afterwards every lane holds the full row sums
    float mm[8] = {m1, m2, m3, m4, m5, m6, m7, m8};
    #pragma unroll
    for (int w = 0; w < 8; ++w) {
        #pragma unroll
        for (int msk = 32; msk >= 1; msk >>= 1)
            mm[w] += __shfl_xor(mm[w], msk, 64);
    }

    // monomial power sums -> Legendre sums (lane 0 writes, N = 1024)
    if (lane == 0) {
        const float M1 = mm[0], M2 = mm[1], M3 = mm[2], M4 = mm[3],
                    M5 = mm[4], M6 = mm[5], M7 = mm[6], M8 = mm[7];
        f32x4 A, B;
        A.x = M1;
        A.y = 1.5f * M2 - 512.f;
        A.z = 2.5f * M3 - 1.5f * M1;
        A.w = 4.375f * M4 - 3.75f * M2 + 384.f;
        B.x = 7.875f * M5 - 8.75f * M3 + 1.875f * M1;
        B.y = 14.4375f * M6 - 19.6875f * M4 + 6.5625f * M2 - 320.f;
        B.z = 26.8125f * M7 - 43.3125f * M5 + 19.6875f * M3 - 2.1875f * M1;
        B.w = 50.2734375f * M8 - 93.84375f * M6 + 54.140625f * M4
            - 9.84375f * M2 + 280.f;
        S_lds[wave][0] = A;
        S_lds[wave][1] = B;
    }
    __syncthreads();

    // ---- phase 2, pass A: o = 2t, 2t+1 ----
    #pragma unroll
    for (int r = 0; r < G; ++r) {
        f32x4 sa = S_lds[r][0];   // S1..S4
        f32x4 sb = S_lds[r][1];   // S5..S8
        f32x2 acc;
        #pragma unroll
        for (int ol = 0; ol < 2; ++ol) {
            const float* c = &ca[9 * ol];
            float a = c[0] * 1024.f;          // w=0: sum of ones
            a = fmaf(c[1], sa.x, a);
            a = fmaf(c[2], sa.y, a);
            a = fmaf(c[3], sa.z, a);
            a = fmaf(c[4], sa.w, a);
            a = fmaf(c[5], sb.x, a);
            a = fmaf(c[6], sb.y, a);
            a = fmaf(c[7], sb.z, a);
            a = fmaf(c[8], sb.w, a);
            acc[ol] = a;
        }
        __builtin_nontemporal_store(acc,
            reinterpret_cast<f32x2*>(out + (size_t)(b0 + r) * O_DIM + 2 * t));
    }

    // ---- phase 2, pass B: o = 512 + 2t, 512 + 2t + 1 ----
    const f32x2* cpB = reinterpret_cast<const f32x2*>(coeffs + 9 * 512 + 18 * (size_t)t);
    float cb[18];
    #pragma unroll
    for (int k = 0; k < 9; ++k) {
        f32x2 v = cpB[k];
        cb[2 * k] = v.x; cb[2 * k + 1] = v.y;
    }
    #pragma unroll
    for (int r = 0; r < G; ++r) {
        f32x4 sa = S_lds[r][0];
        f32x4 sb = S_lds[r][1];
        f32x2 acc;
        #pragma unroll
        for (int ol = 0; ol < 2; ++ol) {
            const float* c = &cb[9 * ol];
            float a = c[0] * 1024.f;
            a = fmaf(c[1], sa.x, a);
            a = fmaf(c[2], sa.y, a);
            a = fmaf(c[3], sa.z, a);
            a = fmaf(c[4], sa.w, a);
            a = fmaf(c[5], sb.x, a);
            a = fmaf(c[6], sb.y, a);
            a = fmaf(c[7], sb.z, a);
            a = fmaf(c[8], sb.w, a);
            acc[ol] = a;
        }
        __builtin_nontemporal_store(acc,
            reinterpret_cast<f32x2*>(out + (size_t)(b0 + r) * O_DIM + 512 + 2 * t));
    }
}

extern "C" void kernel_launch(void* const* d_in, const int* in_sizes, int n_in,
                              void* d_out, int out_size, void* d_ws, size_t ws_size,
                              hipStream_t stream) {
    const float* x      = (const float*)d_in[0];
    const float* coeffs = (const float*)d_in[1];
    const float* scale  = (const float*)d_in[2];
    float* out          = (float*)d_out;

    const int B = in_sizes[0] / I_DIM;   // 4096
    const int nblocks = B / G;           // 1024

    legendre_fused<<<nblocks, NT, 0, stream>>>(x, coeffs, scale, out);
}

// Round 9
// 12.028 us; speedup vs baseline: 1.0596x; 1.0596x over previous
//
#include <hip/hip_runtime.h>

// LegendreActivation: out[b,o] = sum_w coeffs[o,w] * S[b,w]
// where S[b,w] = sum_i P_w(tanh(x[b,i]*scale)),  S[b,0] == 1024 exactly.
//
// R9 = exact revert to R6, the best-measured variant (11.78 us).
// Final structure: power-sum phase 1 (16 ops/elem: 5-op tanh via exp2+rcp,
// 3 power muls, 4 adds + 4 fmacs for M1..M8), 64-lane butterfly, M->S via
// constant monomial matrix (lane 0), phase 2 = 4 outputs/thread x 4 rows,
// coeffs as 9 contiguous float4/thread, nontemporal float4 stores.
// Model: dur = ~10us graph-replay overhead + ~1.8us issue-bound kernel.

constexpr int I_DIM = 1024;
constexpr int O_DIM = 1024;
constexpr int NT    = 256;   // 4 waves
constexpr int G     = 4;     // rows per block, one wave per row

typedef float f32x4 __attribute__((ext_vector_type(4)));

__global__ __launch_bounds__(NT, 4) void legendre_fused(
    const float* __restrict__ x,
    const float* __restrict__ coeffs,
    const float* __restrict__ scale_p,
    float* __restrict__ out)
{
    __shared__ float S_lds[G][8];   // per-row Legendre sums, w = 1..8

    const int t    = threadIdx.x;
    const int wave = t >> 6;        // 0..3 -> owns row b0+wave
    const int lane = t & 63;
    const int b0   = blockIdx.x * G;
    const int row  = b0 + wave;

    // ---- issue all global loads up front ----
    const float4* xr = reinterpret_cast<const float4*>(x + (size_t)row * I_DIM) + lane;
    float4 xv0 = xr[0];
    float4 xv1 = xr[64];
    float4 xv2 = xr[128];
    float4 xv3 = xr[192];

    const float4* ct4 = reinterpret_cast<const float4*>(coeffs) + (size_t)t * 9;
    float4 cv[9];
    #pragma unroll
    for (int k = 0; k < 9; ++k) cv[k] = ct4[k];

    float sc = fminf(fmaxf(scale_p[0], 0.1f), 2.0f);
    const float K = sc * 2.8853900817779268f;  // sc * 2*log2(e)

    // ---- phase 1: power sums M_1..M_8 over one row (64 lanes x 16) ----
    float m1 = 0.f, m2 = 0.f, m3 = 0.f, m4 = 0.f,
          m5 = 0.f, m6 = 0.f, m7 = 0.f, m8 = 0.f;

    const float vals[16] = {xv0.x, xv0.y, xv0.z, xv0.w,
                            xv1.x, xv1.y, xv1.z, xv1.w,
                            xv2.x, xv2.y, xv2.z, xv2.w,
                            xv3.x, xv3.y, xv3.z, xv3.w};
    #pragma unroll
    for (int e = 0; e < 16; ++e) {
        float ex = __builtin_amdgcn_exp2f(vals[e] * K);               // e^{2z}
        float xs = fmaf(-2.f, __builtin_amdgcn_rcpf(ex + 1.f), 1.f);  // tanh
        float p2 = xs * xs;           // mul
        float p3 = p2 * xs;           // mul
        float p4 = p2 * p2;           // mul
        m1 += xs;                     // add
        m2 += p2;                     // add
        m3 += p3;                     // add
        m4 += p4;                     // add
        m5 = fmaf(p2, p3, m5);        // fmac
        m6 = fmaf(p3, p3, m6);        // fmac
        m7 = fmaf(p3, p4, m7);        // fmac
        m8 = fmaf(p4, p4, m8);        // fmac
    }

    // 64-lane butterfly: afterwards every lane holds the full row sums
    float mm[8] = {m1, m2, m3, m4, m5, m6, m7, m8};
    #pragma unroll
    for (int w = 0; w < 8; ++w) {
        #pragma unroll
        for (int msk = 32; msk >= 1; msk >>= 1)
            mm[w] += __shfl_xor(mm[w], msk, 64);
    }

    // monomial power sums -> Legendre sums (lane 0 writes)
    if (lane == 0) {
        const float M1 = mm[0], M2 = mm[1], M3 = mm[2], M4 = mm[3],
                    M5 = mm[4], M6 = mm[5], M7 = mm[6], M8 = mm[7];
        const float N = (float)I_DIM;   // M_0
        S_lds[wave][0] = M1;
        S_lds[wave][1] = 1.5f * M2 - 0.5f * N;
        S_lds[wave][2] = 2.5f * M3 - 1.5f * M1;
        S_lds[wave][3] = 4.375f * M4 - 3.75f * M2 + 0.375f * N;
        S_lds[wave][4] = 7.875f * M5 - 8.75f * M3 + 1.875f * M1;
        S_lds[wave][5] = 14.4375f * M6 - 19.6875f * M4 + 6.5625f * M2 - 0.3125f * N;
        S_lds[wave][6] = 26.8125f * M7 - 43.3125f * M5 + 19.6875f * M3 - 2.1875f * M1;
        S_lds[wave][7] = 50.2734375f * M8 - 93.84375f * M6 + 54.140625f * M4
                       - 9.84375f * M2 + 0.2734375f * N;
    }
    __syncthreads();

    // ---- phase 2: each thread writes out[b0+r][4t..4t+3] for r = 0..3 ----
    // unpack coeffs: c[ol*9 + w]
    float c[36];
    #pragma unroll
    for (int k = 0; k < 9; ++k) {
        c[4 * k + 0] = cv[k].x; c[4 * k + 1] = cv[k].y;
        c[4 * k + 2] = cv[k].z; c[4 * k + 3] = cv[k].w;
    }

    #pragma unroll
    for (int r = 0; r < G; ++r) {
        float s0 = S_lds[r][0], s1 = S_lds[r][1], s2 = S_lds[r][2], s3 = S_lds[r][3];
        float s4 = S_lds[r][4], s5 = S_lds[r][5], s6 = S_lds[r][6], s7 = S_lds[r][7];

        f32x4 acc;
        #pragma unroll
        for (int ol = 0; ol < 4; ++ol) {
            float a = c[ol * 9 + 0] * (float)I_DIM;   // w=0: sum of ones
            a = fmaf(c[ol * 9 + 1], s0, a);
            a = fmaf(c[ol * 9 + 2], s1, a);
            a = fmaf(c[ol * 9 + 3], s2, a);
            a = fmaf(c[ol * 9 + 4], s3, a);
            a = fmaf(c[ol * 9 + 5], s4, a);
            a = fmaf(c[ol * 9 + 6], s5, a);
            a = fmaf(c[ol * 9 + 7], s6, a);
            a = fmaf(c[ol * 9 + 8], s7, a);
            acc[ol] = a;
        }
        // streaming store: don't pollute L2 (keeps x resident across replays)
        __builtin_nontemporal_store(acc,
            reinterpret_cast<f32x4*>(out + (size_t)(b0 + r) * O_DIM + 4 * t));
    }
}

extern "C" void kernel_launch(void* const* d_in, const int* in_sizes, int n_in,
                              void* d_out, int out_size, void* d_ws, size_t ws_size,
                              hipStream_t stream) {
    const float* x      = (const float*)d_in[0];
    const float* coeffs = (const float*)d_in[1];
    const float* scale  = (const float*)d_in[2];
    float* out          = (float*)d_out;

    const int B = in_sizes[0] / I_DIM;   // 4096
    const int nblocks = B / G;           // 1024

    legendre_fused<<<nblocks, NT, 0, stream>>>(x, coeffs, scale, out);
}